// Round 1
// baseline (288.469 us; speedup 1.0000x reference)
//
#include <hip/hip_runtime.h>
#include <stdint.h>

// DynamicsEnsemble forward, MI355X/gfx950.
// Plan: f32 -> bf16 (MFMA), m97-style 128x128/BK32 double-buffered GEMMs.
//   G1: h1 = tanh(state @ W1 + b1)   [E,B,256]  (K=64)
//   G2: h2 = tanh(h1 @ W2 + b2)      [E,B,256]  (K=256)
//   G3: out = (1/8) sum_e h2 @ [Wf|Wg] + mean_e bias   (K = 8*256 = 2048)
// Weights pre-transposed to [N][K] bf16 so both MFMA operands are contiguous
// ds_read_b128 loads. Wf/Wg fused into Wcat_t[1152][2048] (N padded to 9*128).

#define BSZ   16384
#define EDIM  8
#define SDIM  64
#define HDIM  256
#define NOUT  1088          // 64 (f) + 1024 (g)
#define NPAD  1152          // 9 * 128
#define KCAT  2048          // EDIM * HDIM

typedef __attribute__((ext_vector_type(8))) short s16x8;   // 8 x bf16 (4 VGPR)
typedef __attribute__((ext_vector_type(4))) float f32x4;   // MFMA 16x16 acc

__device__ __forceinline__ unsigned short f2bf(float x) {
  unsigned int u = __float_as_uint(x);          // RNE f32->bf16 (finite inputs)
  u += 0x7fffu + ((u >> 16) & 1u);
  return (unsigned short)(u >> 16);
}

__device__ __forceinline__ float fast_tanh(float x) {
  float t = __expf(2.0f * x);                   // saturates: +inf->1, 0->-1
  return 1.0f - 2.0f / (t + 1.0f);
}

__device__ __forceinline__ void gload_lds16(const unsigned short* g, unsigned short* l) {
  // async global->LDS, 16B/lane; LDS dest = wave-uniform base + lane*16
  __builtin_amdgcn_global_load_lds(
      (__attribute__((address_space(1))) void*)(g),
      (__attribute__((address_space(3))) void*)(l), 16, 0, 0);
}

// ---------------- prep kernels ----------------

__global__ void conv_state_kernel(const float* __restrict__ src,
                                  unsigned short* __restrict__ dst) {
  int i = (blockIdx.x * 256 + threadIdx.x) * 4;       // exact: 1M elems
  const float4 v = *reinterpret_cast<const float4*>(src + i);
  ushort4 o;
  o.x = f2bf(v.x); o.y = f2bf(v.y); o.z = f2bf(v.z); o.w = f2bf(v.w);
  *reinterpret_cast<ushort4*>(dst + i) = o;
}

// tiled f32 -> bf16 transpose: dst[c * dPitch + r] = src[r * C + c], per batch z
__global__ void tr_f32_bf16_kernel(const float* __restrict__ src,
                                   unsigned short* __restrict__ dst,
                                   int R, int C, long sBatch, long dBatch, int dPitch) {
  __shared__ float t[32][33];
  src += (size_t)blockIdx.z * sBatch;
  dst += (size_t)blockIdx.z * dBatch;
  const int c0 = blockIdx.x * 32, r0 = blockIdx.y * 32;
  const int tx = threadIdx.x, ty = threadIdx.y;       // (32, 8)
  #pragma unroll
  for (int i = 0; i < 32; i += 8) {
    int r = r0 + ty + i;
    if (r < R && c0 + tx < C) t[ty + i][tx] = src[(size_t)r * C + c0 + tx];
  }
  __syncthreads();
  #pragma unroll
  for (int i = 0; i < 32; i += 8) {
    int c = c0 + ty + i;
    if (c < C && r0 + tx < R)
      dst[(size_t)c * dPitch + (r0 + tx)] = f2bf(t[tx][ty + i]);
  }
}

__global__ void bias_mean_kernel(const float* __restrict__ bf,
                                 const float* __restrict__ bg,
                                 float* __restrict__ bm) {
  int n = blockIdx.x * 256 + threadIdx.x;
  if (n >= NOUT) return;
  float s = 0.f;
  #pragma unroll
  for (int e = 0; e < EDIM; ++e)
    s += (n < SDIM) ? bf[e * SDIM + n] : bg[e * 1024 + (n - SDIM)];
  bm[n] = s * 0.125f;
}

// ---------------- GEMM kernels ----------------
// 256 thr = 4 waves (2x2), BM=BN=128, BK=32, LDS 32KB double-buffered.
// Wave (wr,wc) owns 64x64: acc[4][4] 16x16 frags.
// A: [M][K] row-major bf16; B: [N][K] (transposed weights). Frag reads:
//   lane l: row = base + (l&15), 8 contiguous k at 8*(l>>4)  -> ds_read_b128.
// C/D: col = l&15, row = 4*(l>>4)+reg  (m89-verified orientation).

template <int KK>
__global__ __launch_bounds__(256) void gemm_tanh_kernel(
    const unsigned short* __restrict__ Ab,   // + e*aStride, [M][KK]
    const unsigned short* __restrict__ Bb,   // per-e [256][KK]
    const float* __restrict__ biasb,         // [E][256] f32
    unsigned short* __restrict__ houtb,      // [E][M][256] bf16
    long aStride) {
  __shared__ unsigned short As[2][4096];
  __shared__ unsigned short Bs[2][4096];
  const int tid = threadIdx.x;
  const int lane = tid & 63;
  const int wv = tid >> 6;
  const int wr = wv >> 1, wc = wv & 1;
  const int mtile = blockIdx.x * 128;
  const int ntile = blockIdx.y * 128;
  const int e = blockIdx.z;
  const unsigned short* Ag = Ab + (size_t)e * aStride;
  const unsigned short* Bg = Bb + (size_t)e * (HDIM * KK);
  const float* bias = biasb + e * HDIM;
  unsigned short* hout = houtb + (size_t)e * ((size_t)BSZ * HDIM);
  const int lr = lane & 15, lk = lane >> 4;

  f32x4 acc[4][4];
  #pragma unroll
  for (int i = 0; i < 4; ++i)
    #pragma unroll
    for (int j = 0; j < 4; ++j) acc[i][j] = (f32x4){0.f, 0.f, 0.f, 0.f};

  auto stage = [&](int buf, int kk) {
    #pragma unroll
    for (int i = 0; i < 2; ++i) {
      const int s0 = wv * 64 + i * 256;   // wave-uniform 16B-slot base
      const int s = s0 + lane;
      const int row = s >> 2;
      const int w = s & 3;
      gload_lds16(Ag + (size_t)(mtile + row) * KK + (kk + w * 8), &As[buf][s0 * 8]);
      gload_lds16(Bg + (size_t)(ntile + row) * KK + (kk + w * 8), &Bs[buf][s0 * 8]);
    }
  };

  stage(0, 0);
  __syncthreads();
  constexpr int NSTEP = KK / 32;
  #pragma unroll
  for (int t = 0; t < NSTEP; ++t) {
    const int cur = t & 1;
    if (t + 1 < NSTEP) stage(cur ^ 1, (t + 1) * 32);
    s16x8 av[4], bv[4];
    #pragma unroll
    for (int mi = 0; mi < 4; ++mi)
      av[mi] = *(const s16x8*)&As[cur][(wr * 64 + mi * 16 + lr) * 32 + lk * 8];
    #pragma unroll
    for (int nj = 0; nj < 4; ++nj)
      bv[nj] = *(const s16x8*)&Bs[cur][(wc * 64 + nj * 16 + lr) * 32 + lk * 8];
    #pragma unroll
    for (int mi = 0; mi < 4; ++mi)
      #pragma unroll
      for (int nj = 0; nj < 4; ++nj)
        acc[mi][nj] = __builtin_amdgcn_mfma_f32_16x16x32_bf16(av[mi], bv[nj], acc[mi][nj], 0, 0, 0);
    __syncthreads();
  }

  #pragma unroll
  for (int nj = 0; nj < 4; ++nj) {
    const int col = ntile + wc * 64 + nj * 16 + lr;
    const float bc = bias[col];
    #pragma unroll
    for (int mi = 0; mi < 4; ++mi)
      #pragma unroll
      for (int r = 0; r < 4; ++r) {
        const int row = mtile + wr * 64 + mi * 16 + lk * 4 + r;
        hout[(size_t)row * HDIM + col] = f2bf(fast_tanh(acc[mi][nj][r] + bc));
      }
  }
}

__global__ __launch_bounds__(256) void gemm_out_kernel(
    const unsigned short* __restrict__ h2b,   // [E][B][256] bf16
    const unsigned short* __restrict__ Wcat,  // [1152][2048] bf16 (pad rows zeroed)
    const float* __restrict__ bm,             // [1088] f32 mean bias
    float* __restrict__ out) {
  __shared__ unsigned short As[2][4096];
  __shared__ unsigned short Bs[2][4096];
  const int tid = threadIdx.x;
  const int lane = tid & 63;
  const int wv = tid >> 6;
  const int wr = wv >> 1, wc = wv & 1;
  const int mtile = blockIdx.x * 128;
  const int ntile = blockIdx.y * 128;
  const int lr = lane & 15, lk = lane >> 4;

  f32x4 acc[4][4];
  #pragma unroll
  for (int i = 0; i < 4; ++i)
    #pragma unroll
    for (int j = 0; j < 4; ++j) acc[i][j] = (f32x4){0.f, 0.f, 0.f, 0.f};

  auto stage = [&](int buf, int kk) {
    const int e = kk >> 8;              // which ensemble member
    const int kl = kk & 255;            // k within member
    #pragma unroll
    for (int i = 0; i < 2; ++i) {
      const int s0 = wv * 64 + i * 256;
      const int s = s0 + lane;
      const int row = s >> 2;
      const int w = s & 3;
      gload_lds16(h2b + ((size_t)e * BSZ + mtile + row) * HDIM + (kl + w * 8),
                  &As[buf][s0 * 8]);
      gload_lds16(Wcat + (size_t)(ntile + row) * KCAT + (kk + w * 8),
                  &Bs[buf][s0 * 8]);
    }
  };

  stage(0, 0);
  __syncthreads();
  constexpr int NSTEP = KCAT / 32;      // 64
  #pragma unroll 2
  for (int t = 0; t < NSTEP; ++t) {
    const int cur = t & 1;
    if (t + 1 < NSTEP) stage(cur ^ 1, (t + 1) * 32);
    s16x8 av[4], bv[4];
    #pragma unroll
    for (int mi = 0; mi < 4; ++mi)
      av[mi] = *(const s16x8*)&As[cur][(wr * 64 + mi * 16 + lr) * 32 + lk * 8];
    #pragma unroll
    for (int nj = 0; nj < 4; ++nj)
      bv[nj] = *(const s16x8*)&Bs[cur][(wc * 64 + nj * 16 + lr) * 32 + lk * 8];
    #pragma unroll
    for (int mi = 0; mi < 4; ++mi)
      #pragma unroll
      for (int nj = 0; nj < 4; ++nj)
        acc[mi][nj] = __builtin_amdgcn_mfma_f32_16x16x32_bf16(av[mi], bv[nj], acc[mi][nj], 0, 0, 0);
    __syncthreads();
  }

  #pragma unroll
  for (int nj = 0; nj < 4; ++nj) {
    const int col = ntile + wc * 64 + nj * 16 + lr;
    if (col < NOUT) {
      const float bc = bm[col];
      #pragma unroll
      for (int mi = 0; mi < 4; ++mi)
        #pragma unroll
        for (int r = 0; r < 4; ++r) {
          const int row = mtile + wr * 64 + mi * 16 + lk * 4 + r;
          const float v = acc[mi][nj][r] * 0.125f + bc;
          if (col < SDIM) out[(size_t)row * SDIM + col] = v;                         // f_mean
          else out[(size_t)BSZ * SDIM + (size_t)row * 1024 + (col - SDIM)] = v;      // g_mean
        }
    }
  }
}

// ---------------- launch ----------------

extern "C" void kernel_launch(void* const* d_in, const int* in_sizes, int n_in,
                              void* d_out, int out_size, void* d_ws, size_t ws_size,
                              hipStream_t stream) {
  (void)in_sizes; (void)n_in; (void)out_size;
  const float* state = (const float*)d_in[0];
  const float* W1 = (const float*)d_in[1];
  const float* b1 = (const float*)d_in[2];
  const float* W2 = (const float*)d_in[3];
  const float* b2 = (const float*)d_in[4];
  const float* Wf = (const float*)d_in[5];
  const float* bf = (const float*)d_in[6];
  const float* Wg = (const float*)d_in[7];
  const float* bg = (const float*)d_in[8];
  float* out = (float*)d_out;

  // ws layout (bytes)
  const size_t SZ_SB   = (size_t)BSZ * SDIM * 2;                 //   2 MB
  const size_t SZ_H    = (size_t)EDIM * BSZ * HDIM * 2;          //  64 MB each
  const size_t SZ_W1T  = (size_t)EDIM * HDIM * SDIM * 2;
  const size_t SZ_W2T  = (size_t)EDIM * HDIM * HDIM * 2;
  const size_t SZ_WCAT = (size_t)NPAD * KCAT * 2;
  const size_t SZ_BM   = (size_t)NOUT * 4;
  const size_t OFF_SB = 0;
  const size_t OFF_H1 = OFF_SB + SZ_SB;
  const size_t OFF_H2 = OFF_H1 + SZ_H;
  const size_t OFF_W1T = OFF_H2 + SZ_H;
  const size_t OFF_W2T = OFF_W1T + SZ_W1T;
  const size_t OFF_WCAT = OFF_W2T + SZ_W2T;
  const size_t OFF_BM = OFF_WCAT + SZ_WCAT;
  const size_t TOTAL = OFF_BM + SZ_BM;                            // ~142.4 MB
  if (ws_size < TOTAL) return;  // ws too small: leave out poisoned (clean fail signal)

  char* ws = (char*)d_ws;
  unsigned short* sB   = (unsigned short*)(ws + OFF_SB);
  unsigned short* h1B  = (unsigned short*)(ws + OFF_H1);
  unsigned short* h2B  = (unsigned short*)(ws + OFF_H2);
  unsigned short* W1t  = (unsigned short*)(ws + OFF_W1T);
  unsigned short* W2t  = (unsigned short*)(ws + OFF_W2T);
  unsigned short* Wcat = (unsigned short*)(ws + OFF_WCAT);
  float* bm            = (float*)(ws + OFF_BM);

  hipMemsetAsync(Wcat, 0, SZ_WCAT, stream);   // zero N-pad rows 1088..1151
  conv_state_kernel<<<1024, 256, 0, stream>>>(state, sB);
  dim3 tb(32, 8);
  // W1t[e][h][s] = W1[e][s][h]
  tr_f32_bf16_kernel<<<dim3(8, 2, 8), tb, 0, stream>>>(W1, W1t, 64, 256,
      (long)64 * 256, (long)256 * 64, 64);
  // W2t[e][j][h] = W2[e][h][j]
  tr_f32_bf16_kernel<<<dim3(8, 8, 8), tb, 0, stream>>>(W2, W2t, 256, 256,
      65536L, 65536L, 256);
  // Wcat[n][e*256+h] = Wf[e][h][n]            (rows 0..63)
  tr_f32_bf16_kernel<<<dim3(2, 8, 8), tb, 0, stream>>>(Wf, Wcat, 256, 64,
      (long)256 * 64, 256L, KCAT);
  // Wcat[64+n][e*256+h] = Wg[e][h][n]         (rows 64..1087)
  tr_f32_bf16_kernel<<<dim3(32, 8, 8), tb, 0, stream>>>(Wg, Wcat + 64 * KCAT, 256, 1024,
      (long)256 * 1024, 256L, KCAT);
  bias_mean_kernel<<<5, 256, 0, stream>>>(bf, bg, bm);

  gemm_tanh_kernel<64><<<dim3(128, 2, 8), 256, 0, stream>>>(sB, W1t, b1, h1B, 0L);
  gemm_tanh_kernel<256><<<dim3(128, 2, 8), 256, 0, stream>>>(h1B, W2t, b2, h2B,
      (long)BSZ * HDIM);
  gemm_out_kernel<<<dim3(128, 9), 256, 0, stream>>>(h2B, Wcat, bm, out);
}

// Round 2
// 265.616 us; speedup vs baseline: 1.0860x; 1.0860x over previous
//
#include <hip/hip_runtime.h>
#include <stdint.h>

// DynamicsEnsemble forward, MI355X/gfx950. Round 2.
//   G1: h1 = tanh(state @ W1 + b1)   [E,B,256]  (K=64)
//   G2: h2 = tanh(h1 @ W2 + b2)      [E,B,256]  (K=256)
//   G3: out = (1/8) sum_e h2 @ [Wf|Wg] + mean_e bias   (K = 8*256 = 2048)
// R2 changes vs R1:
//  - T2 involution swizzle on LDS tiles (linear global_load_lds dest,
//    inverse-swizzled global source, swizzled ds_read): slot^((row>>1)&3)
//    -> 8-way bank conflict (9.4M cycles) becomes 2-way (free).
//  - gemm_out: BN 128->192 (1152 = 6*192, zero extra pad), grid 768 = 3/CU
//    exact pack via __launch_bounds__(256,3); per-wave 64x96 (acc[4][6]).
//  - T1 XCD-chunked block remap in gemm_out (m-major inside chunk) so the
//    6 N-blocks sharing an A-slab are co-resident on one XCD -> L2 hits.
//  - T5 setprio around MFMA cluster.

#define BSZ   16384
#define EDIM  8
#define SDIM  64
#define HDIM  256
#define NOUT  1088          // 64 (f) + 1024 (g)
#define NPAD  1152          // 6 * 192
#define KCAT  2048          // EDIM * HDIM

typedef __attribute__((ext_vector_type(8))) short s16x8;   // 8 x bf16 (4 VGPR)
typedef __attribute__((ext_vector_type(4))) float f32x4;   // MFMA 16x16 acc

__device__ __forceinline__ unsigned short f2bf(float x) {
  unsigned int u = __float_as_uint(x);          // RNE f32->bf16 (finite inputs)
  u += 0x7fffu + ((u >> 16) & 1u);
  return (unsigned short)(u >> 16);
}

__device__ __forceinline__ float fast_tanh(float x) {
  float t = __expf(2.0f * x);                   // saturates: +inf->1, 0->-1
  return 1.0f - 2.0f / (t + 1.0f);
}

__device__ __forceinline__ void gload_lds16(const unsigned short* g, unsigned short* l) {
  // async global->LDS, 16B/lane; LDS dest = wave-uniform base + lane*16
  __builtin_amdgcn_global_load_lds(
      (__attribute__((address_space(1))) void*)(g),
      (__attribute__((address_space(3))) void*)(l), 16, 0, 0);
}

// swizzle for [R][32] bf16 tiles (64B rows): 16B-slot sigma -> sigma ^ ((row>>1)&3)
// read at (row, lk) uses slot lk^((row>>1)&3); stage puts global slot
// kap = sigma^((row>>1)&3) at LDS slot sigma. Involution -> read gets lk. Banks:
// 16 rows x fixed lk -> 8 distinct bank-quads (parity bit + 4 slots) = 2-way = free.
__device__ __forceinline__ int swz_slot(int row, int sl) { return sl ^ ((row >> 1) & 3); }

// ---------------- prep kernels ----------------

__global__ void conv_state_kernel(const float* __restrict__ src,
                                  unsigned short* __restrict__ dst) {
  int i = (blockIdx.x * 256 + threadIdx.x) * 4;       // exact: 1M elems
  const float4 v = *reinterpret_cast<const float4*>(src + i);
  ushort4 o;
  o.x = f2bf(v.x); o.y = f2bf(v.y); o.z = f2bf(v.z); o.w = f2bf(v.w);
  *reinterpret_cast<ushort4*>(dst + i) = o;
}

// tiled f32 -> bf16 transpose: dst[c * dPitch + r] = src[r * C + c], per batch z
__global__ void tr_f32_bf16_kernel(const float* __restrict__ src,
                                   unsigned short* __restrict__ dst,
                                   int R, int C, long sBatch, long dBatch, int dPitch) {
  __shared__ float t[32][33];
  src += (size_t)blockIdx.z * sBatch;
  dst += (size_t)blockIdx.z * dBatch;
  const int c0 = blockIdx.x * 32, r0 = blockIdx.y * 32;
  const int tx = threadIdx.x, ty = threadIdx.y;       // (32, 8)
  #pragma unroll
  for (int i = 0; i < 32; i += 8) {
    int r = r0 + ty + i;
    if (r < R && c0 + tx < C) t[ty + i][tx] = src[(size_t)r * C + c0 + tx];
  }
  __syncthreads();
  #pragma unroll
  for (int i = 0; i < 32; i += 8) {
    int c = c0 + ty + i;
    if (c < C && r0 + tx < R)
      dst[(size_t)c * dPitch + (r0 + tx)] = f2bf(t[tx][ty + i]);
  }
}

__global__ void bias_mean_kernel(const float* __restrict__ bf,
                                 const float* __restrict__ bg,
                                 float* __restrict__ bm) {
  int n = blockIdx.x * 256 + threadIdx.x;
  if (n >= NOUT) return;
  float s = 0.f;
  #pragma unroll
  for (int e = 0; e < EDIM; ++e)
    s += (n < SDIM) ? bf[e * SDIM + n] : bg[e * 1024 + (n - SDIM)];
  bm[n] = s * 0.125f;
}

// ---------------- GEMM kernels ----------------
// A: [M][K] row-major bf16; B: [N][K] (transposed weights). Frag reads:
//   lane l: row = base + (l&15), 8 contiguous k at 8*(l>>4)  -> ds_read_b128.
// C/D: col = l&15, row = 4*(l>>4)+reg  (m89-verified orientation).

template <int KK>
__global__ __launch_bounds__(256) void gemm_tanh_kernel(
    const unsigned short* __restrict__ Ab,   // + e*aStride, [M][KK]
    const unsigned short* __restrict__ Bb,   // per-e [256][KK]
    const float* __restrict__ biasb,         // [E][256] f32
    unsigned short* __restrict__ houtb,      // [E][M][256] bf16
    long aStride) {
  __shared__ unsigned short As[2][4096];
  __shared__ unsigned short Bs[2][4096];
  const int tid = threadIdx.x;
  const int lane = tid & 63;
  const int wv = tid >> 6;
  const int wr = wv >> 1, wc = wv & 1;
  const int mtile = blockIdx.x * 128;
  const int ntile = blockIdx.y * 128;
  const int e = blockIdx.z;
  const unsigned short* Ag = Ab + (size_t)e * aStride;
  const unsigned short* Bg = Bb + (size_t)e * (HDIM * KK);
  const float* bias = biasb + e * HDIM;
  unsigned short* hout = houtb + (size_t)e * ((size_t)BSZ * HDIM);
  const int lr = lane & 15, lk = lane >> 4;

  f32x4 acc[4][4];
  #pragma unroll
  for (int i = 0; i < 4; ++i)
    #pragma unroll
    for (int j = 0; j < 4; ++j) acc[i][j] = (f32x4){0.f, 0.f, 0.f, 0.f};

  auto stage = [&](int buf, int kk) {
    #pragma unroll
    for (int i = 0; i < 2; ++i) {
      const int s0 = wv * 64 + i * 256;   // wave-uniform 16B-slot base
      const int s = s0 + lane;
      const int row = s >> 2;
      const int kap = swz_slot(row, s & 3);
      gload_lds16(Ag + (size_t)(mtile + row) * KK + (kk + kap * 8), &As[buf][s0 * 8]);
      gload_lds16(Bg + (size_t)(ntile + row) * KK + (kk + kap * 8), &Bs[buf][s0 * 8]);
    }
  };

  stage(0, 0);
  __syncthreads();
  constexpr int NSTEP = KK / 32;
  #pragma unroll
  for (int t = 0; t < NSTEP; ++t) {
    const int cur = t & 1;
    if (t + 1 < NSTEP) stage(cur ^ 1, (t + 1) * 32);
    s16x8 av[4], bv[4];
    #pragma unroll
    for (int mi = 0; mi < 4; ++mi) {
      const int r = wr * 64 + mi * 16 + lr;
      av[mi] = *(const s16x8*)&As[cur][r * 32 + swz_slot(r, lk) * 8];
    }
    #pragma unroll
    for (int nj = 0; nj < 4; ++nj) {
      const int r = wc * 64 + nj * 16 + lr;
      bv[nj] = *(const s16x8*)&Bs[cur][r * 32 + swz_slot(r, lk) * 8];
    }
    __builtin_amdgcn_s_setprio(1);
    #pragma unroll
    for (int mi = 0; mi < 4; ++mi)
      #pragma unroll
      for (int nj = 0; nj < 4; ++nj)
        acc[mi][nj] = __builtin_amdgcn_mfma_f32_16x16x32_bf16(av[mi], bv[nj], acc[mi][nj], 0, 0, 0);
    __builtin_amdgcn_s_setprio(0);
    __syncthreads();
  }

  #pragma unroll
  for (int nj = 0; nj < 4; ++nj) {
    const int col = ntile + wc * 64 + nj * 16 + lr;
    const float bc = bias[col];
    #pragma unroll
    for (int mi = 0; mi < 4; ++mi)
      #pragma unroll
      for (int r = 0; r < 4; ++r) {
        const int row = mtile + wr * 64 + mi * 16 + lk * 4 + r;
        hout[(size_t)row * HDIM + col] = f2bf(fast_tanh(acc[mi][nj][r] + bc));
      }
  }
}

// gemm_out: BM=128, BN=192, BK=32. 4 waves (2x2), wave owns 64x96 (acc[4][6]).
// Grid 768 = 128 m-tiles * 6 n-tiles = exactly 3 blocks/CU (launch_bounds(256,3)).
// LDS: A 2*8KB + B 2*12KB = 40KB.
__global__ __launch_bounds__(256, 3) void gemm_out_kernel(
    const unsigned short* __restrict__ h2b,   // [E][B][256] bf16
    const unsigned short* __restrict__ Wcat,  // [1152][2048] bf16 (pad rows zeroed)
    const float* __restrict__ bm,             // [1088] f32 mean bias
    float* __restrict__ out) {
  __shared__ unsigned short As[2][4096];      // [128][32]
  __shared__ unsigned short Bs[2][6144];      // [192][32]
  const int tid = threadIdx.x;
  const int lane = tid & 63;
  const int wv = tid >> 6;
  const int wr = wv >> 1, wc = wv & 1;
  // T1: XCD-chunked remap. HW round-robins consecutive blockIdx across 8 XCDs;
  // logical = (bid%8)*96 + bid/8 gives each XCD one contiguous chunk of 96
  // logical blocks = 16 m-tiles x 6 n-tiles (m-major) -> all 6 sharers of an
  // A-slab (512KB) co-resident on one XCD's L2. 768%8==0 -> bijective.
  const int logical = (blockIdx.x & 7) * 96 + (blockIdx.x >> 3);
  const int mtile = (logical / 6) * 128;
  const int ntile = (logical % 6) * 192;
  const int lr = lane & 15, lk = lane >> 4;

  f32x4 acc[4][6];
  #pragma unroll
  for (int i = 0; i < 4; ++i)
    #pragma unroll
    for (int j = 0; j < 6; ++j) acc[i][j] = (f32x4){0.f, 0.f, 0.f, 0.f};

  auto stage = [&](int buf, int kk) {
    const int e = kk >> 8;              // which ensemble member
    const int kl = kk & 255;            // k within member
    #pragma unroll
    for (int i = 0; i < 2; ++i) {       // A: 512 slots
      const int s0 = wv * 64 + i * 256;
      const int s = s0 + lane;
      const int row = s >> 2;
      const int kap = swz_slot(row, s & 3);
      gload_lds16(h2b + ((size_t)e * BSZ + mtile + row) * HDIM + (kl + kap * 8),
                  &As[buf][s0 * 8]);
    }
    #pragma unroll
    for (int i = 0; i < 3; ++i) {       // B: 768 slots
      const int s0 = wv * 64 + i * 256;
      const int s = s0 + lane;
      const int row = s >> 2;
      const int kap = swz_slot(row, s & 3);
      gload_lds16(Wcat + (size_t)(ntile + row) * KCAT + (kk + kap * 8),
                  &Bs[buf][s0 * 8]);
    }
  };

  stage(0, 0);
  __syncthreads();
  constexpr int NSTEP = KCAT / 32;      // 64
  #pragma unroll 2
  for (int t = 0; t < NSTEP; ++t) {
    const int cur = t & 1;
    if (t + 1 < NSTEP) stage(cur ^ 1, (t + 1) * 32);
    s16x8 av[4], bv[6];
    #pragma unroll
    for (int mi = 0; mi < 4; ++mi) {
      const int r = wr * 64 + mi * 16 + lr;
      av[mi] = *(const s16x8*)&As[cur][r * 32 + swz_slot(r, lk) * 8];
    }
    #pragma unroll
    for (int nj = 0; nj < 6; ++nj) {
      const int r = wc * 96 + nj * 16 + lr;
      bv[nj] = *(const s16x8*)&Bs[cur][r * 32 + swz_slot(r, lk) * 8];
    }
    __builtin_amdgcn_s_setprio(1);
    #pragma unroll
    for (int mi = 0; mi < 4; ++mi)
      #pragma unroll
      for (int nj = 0; nj < 6; ++nj)
        acc[mi][nj] = __builtin_amdgcn_mfma_f32_16x16x32_bf16(av[mi], bv[nj], acc[mi][nj], 0, 0, 0);
    __builtin_amdgcn_s_setprio(0);
    __syncthreads();
  }

  #pragma unroll
  for (int nj = 0; nj < 6; ++nj) {
    const int col = ntile + wc * 96 + nj * 16 + lr;
    if (col < NOUT) {
      const float bc = bm[col];
      #pragma unroll
      for (int mi = 0; mi < 4; ++mi)
        #pragma unroll
        for (int r = 0; r < 4; ++r) {
          const int row = mtile + wr * 64 + mi * 16 + lk * 4 + r;
          const float v = acc[mi][nj][r] * 0.125f + bc;
          if (col < SDIM) out[(size_t)row * SDIM + col] = v;                         // f_mean
          else out[(size_t)BSZ * SDIM + (size_t)row * 1024 + (col - SDIM)] = v;      // g_mean
        }
    }
  }
}

// ---------------- launch ----------------

extern "C" void kernel_launch(void* const* d_in, const int* in_sizes, int n_in,
                              void* d_out, int out_size, void* d_ws, size_t ws_size,
                              hipStream_t stream) {
  (void)in_sizes; (void)n_in; (void)out_size;
  const float* state = (const float*)d_in[0];
  const float* W1 = (const float*)d_in[1];
  const float* b1 = (const float*)d_in[2];
  const float* W2 = (const float*)d_in[3];
  const float* b2 = (const float*)d_in[4];
  const float* Wf = (const float*)d_in[5];
  const float* bf = (const float*)d_in[6];
  const float* Wg = (const float*)d_in[7];
  const float* bg = (const float*)d_in[8];
  float* out = (float*)d_out;

  // ws layout (bytes)
  const size_t SZ_SB   = (size_t)BSZ * SDIM * 2;                 //   2 MB
  const size_t SZ_H    = (size_t)EDIM * BSZ * HDIM * 2;          //  64 MB each
  const size_t SZ_W1T  = (size_t)EDIM * HDIM * SDIM * 2;
  const size_t SZ_W2T  = (size_t)EDIM * HDIM * HDIM * 2;
  const size_t SZ_WCAT = (size_t)NPAD * KCAT * 2;
  const size_t SZ_BM   = (size_t)NOUT * 4;
  const size_t OFF_SB = 0;
  const size_t OFF_H1 = OFF_SB + SZ_SB;
  const size_t OFF_H2 = OFF_H1 + SZ_H;
  const size_t OFF_W1T = OFF_H2 + SZ_H;
  const size_t OFF_W2T = OFF_W1T + SZ_W1T;
  const size_t OFF_WCAT = OFF_W2T + SZ_W2T;
  const size_t OFF_BM = OFF_WCAT + SZ_WCAT;
  const size_t TOTAL = OFF_BM + SZ_BM;                            // ~142.4 MB
  if (ws_size < TOTAL) return;  // ws too small: leave out poisoned (clean fail signal)

  char* ws = (char*)d_ws;
  unsigned short* sB   = (unsigned short*)(ws + OFF_SB);
  unsigned short* h1B  = (unsigned short*)(ws + OFF_H1);
  unsigned short* h2B  = (unsigned short*)(ws + OFF_H2);
  unsigned short* W1t  = (unsigned short*)(ws + OFF_W1T);
  unsigned short* W2t  = (unsigned short*)(ws + OFF_W2T);
  unsigned short* Wcat = (unsigned short*)(ws + OFF_WCAT);
  float* bm            = (float*)(ws + OFF_BM);

  hipMemsetAsync(Wcat, 0, SZ_WCAT, stream);   // zero N-pad rows 1088..1151
  conv_state_kernel<<<1024, 256, 0, stream>>>(state, sB);
  dim3 tb(32, 8);
  // W1t[e][h][s] = W1[e][s][h]
  tr_f32_bf16_kernel<<<dim3(8, 2, 8), tb, 0, stream>>>(W1, W1t, 64, 256,
      (long)64 * 256, (long)256 * 64, 64);
  // W2t[e][j][h] = W2[e][h][j]
  tr_f32_bf16_kernel<<<dim3(8, 8, 8), tb, 0, stream>>>(W2, W2t, 256, 256,
      65536L, 65536L, 256);
  // Wcat[n][e*256+h] = Wf[e][h][n]            (rows 0..63)
  tr_f32_bf16_kernel<<<dim3(2, 8, 8), tb, 0, stream>>>(Wf, Wcat, 256, 64,
      (long)256 * 64, 256L, KCAT);
  // Wcat[64+n][e*256+h] = Wg[e][h][n]         (rows 64..1087)
  tr_f32_bf16_kernel<<<dim3(32, 8, 8), tb, 0, stream>>>(Wg, Wcat + 64 * KCAT, 256, 1024,
      (long)256 * 1024, 256L, KCAT);
  bias_mean_kernel<<<5, 256, 0, stream>>>(bf, bg, bm);

  gemm_tanh_kernel<64><<<dim3(128, 2, 8), 256, 0, stream>>>(sB, W1t, b1, h1B, 0L);
  gemm_tanh_kernel<256><<<dim3(128, 2, 8), 256, 0, stream>>>(h1B, W2t, b2, h2B,
      (long)BSZ * HDIM);
  gemm_out_kernel<<<768, 256, 0, stream>>>(h2B, Wcat, bm, out);
}

// Round 5
// 244.277 us; speedup vs baseline: 1.1809x; 1.0874x over previous
//
#include <hip/hip_runtime.h>
#include <stdint.h>

// DynamicsEnsemble forward, MI355X/gfx950. Round 3 design (2nd resubmit:
// R3+R4 both hit broker GPUAcquisitionTimeout; no counters yet).
// 3 dispatches (was 10): prep (weight transposes) -> gemm12 (fused G1+G2)
// -> gemm_out (R2-verified inner loop, bias inlined).
//   G1: h1 = tanh(state @ W1 + b1)   per (m-tile,e), h1 kept in LDS
//   G2: h2 = tanh(h1 @ W2 + b2)      -> global [E][B][256] bf16
//   G3: out = (1/8) sum_e h2 @ [Wf|Wg] + mean_e bias
// All LDS tiles use the R2-verified involution swizzle (slot ^ ((row>>1)&3)):
// linear global_load_lds dest + inverse-swizzled global src + swizzled ds_read.

#define BSZ   16384
#define EDIM  8
#define SDIM  64
#define HDIM  256
#define NOUT  1088          // 64 (f) + 1024 (g)
#define NPAD  1152          // 6 * 192
#define KCAT  2048          // EDIM * HDIM

typedef __attribute__((ext_vector_type(8))) short s16x8;   // 8 x bf16 (4 VGPR)
typedef __attribute__((ext_vector_type(4))) float f32x4;   // MFMA 16x16 acc

__device__ __forceinline__ unsigned short f2bf(float x) {
  unsigned int u = __float_as_uint(x);          // RNE f32->bf16 (finite inputs)
  u += 0x7fffu + ((u >> 16) & 1u);
  return (unsigned short)(u >> 16);
}

__device__ __forceinline__ float fast_tanh(float x) {
  float t = __expf(2.0f * x);                   // saturates: +inf->1, 0->-1
  return 1.0f - 2.0f / (t + 1.0f);
}

__device__ __forceinline__ void gload_lds16(const unsigned short* g, unsigned short* l) {
  // async global->LDS, 16B/lane; LDS dest = wave-uniform base + lane*16
  __builtin_amdgcn_global_load_lds(
      (__attribute__((address_space(1))) void*)(g),
      (__attribute__((address_space(3))) void*)(l), 16, 0, 0);
}

// [R][32]-bf16 K-panels (64B rows of 4 16B slots): physical slot = sl ^ ((row>>1)&3).
// 16 rows x fixed logical slot -> 8 bank-quads -> 2-way = free (m136).
__device__ __forceinline__ int swz_slot(int row, int sl) { return sl ^ ((row >> 1) & 3); }

// ---------------- prep: all weight transposes in ONE kernel ----------------

__device__ __forceinline__ void tr_tile(float (*t)[33],
    const float* __restrict__ src, unsigned short* __restrict__ dst,
    int R, int C, int dPitch, int bx, int by, int tid) {
  const int tx = tid & 31, ty = tid >> 5;       // 32 x 8
  const int c0 = bx * 32, r0 = by * 32;
  #pragma unroll
  for (int i = 0; i < 32; i += 8) {
    int r = r0 + ty + i;
    if (r < R && c0 + tx < C) t[ty + i][tx] = src[(size_t)r * C + c0 + tx];
  }
  __syncthreads();
  #pragma unroll
  for (int i = 0; i < 32; i += 8) {
    int c = c0 + ty + i;
    if (c < C && r0 + tx < R)
      dst[(size_t)c * dPitch + (r0 + tx)] = f2bf(t[tx][ty + i]);
  }
}

__global__ void prep_kernel(const float* __restrict__ W1, const float* __restrict__ W2,
                            const float* __restrict__ Wf, const float* __restrict__ Wg,
                            unsigned short* __restrict__ W1t,
                            unsigned short* __restrict__ W2t,
                            unsigned short* __restrict__ Wcat) {
  __shared__ float t[32][33];
  const int bid = blockIdx.x;
  const int tid = threadIdx.x;
  if (bid < 128) {                    // W1t[e][h][s] <- W1[e][s][h]: 16 blocks/e
    const int e = bid >> 4, r = bid & 15;
    tr_tile(t, W1 + (size_t)e * 64 * 256, W1t + (size_t)e * 256 * 64,
            64, 256, 64, r & 7, r >> 3, tid);
  } else if (bid < 640) {             // W2t[e][j][h] <- W2[e][h][j]: 64 blocks/e
    const int b = bid - 128, e = b >> 6, r = b & 63;
    tr_tile(t, W2 + (size_t)e * 65536, W2t + (size_t)e * 65536,
            256, 256, 256, r & 7, r >> 3, tid);
  } else if (bid < 768) {             // Wcat[n][e*256+h] <- Wf[e][h][n]: 16/e
    const int b = bid - 640, e = b >> 4, r = b & 15;
    tr_tile(t, Wf + (size_t)e * 256 * 64, Wcat + (size_t)e * 256,
            256, 64, KCAT, r & 1, r >> 1, tid);
  } else if (bid < 2816) {            // Wcat[64+n][e*256+h] <- Wg[e][h][n]: 256/e
    const int b = bid - 768, e = b >> 8, r = b & 255;
    tr_tile(t, Wg + (size_t)e * 256 * 1024, Wcat + 64 * KCAT + (size_t)e * 256,
            256, 1024, KCAT, r & 31, r >> 5, tid);
  } else {                            // zero pad rows 1088..1151 (64 rows x 2048)
    const int b = bid - 2816;         // 0..63, one row per block
    const size_t base = (size_t)1088 * KCAT + (size_t)b * KCAT + (size_t)tid * 8;
    const ushort4 z = {0, 0, 0, 0};
    *(ushort4*)&Wcat[base] = z;
    *(ushort4*)&Wcat[base + 4] = z;
  }
}

// ---------------- gemm12: fused G1+G2 per (m-tile of 64, e) ----------------
// 4 waves (2x2 over 64 rows x 256 cols); wave owns 32x128 -> acc[2][8].
// LDS 72KB -> 2 blocks/CU: X1 state 2 panels [64][32] (8KB),
// X2 = W1t 2 panels [256][32] (32KB) reused as h1 8 panels [64][32] (32KB),
// X3 = W2t double-buffer 2 x [256][32] (32KB).
__global__ __launch_bounds__(256) void gemm12_kernel(
    const float* __restrict__ stateF,        // [B][64] f32
    const unsigned short* __restrict__ W1t,  // [E][256][64] bf16
    const float* __restrict__ b1,            // [E][256]
    const unsigned short* __restrict__ W2t,  // [E][256][256] bf16
    const float* __restrict__ b2,            // [E][256]
    unsigned short* __restrict__ h2B) {      // [E][B][256] bf16
  __shared__ unsigned short X1[4096];
  __shared__ unsigned short X2[16384];
  __shared__ unsigned short X3[2][8192];
  const int tid = threadIdx.x, lane = tid & 63, wv = tid >> 6;
  const int wr = wv >> 1, wc = wv & 1;
  const int lr = lane & 15, lk = lane >> 4;
  const int e = blockIdx.x & 7;              // e == XCD (round-robin) -> W2t L2-hot
  const int mtile = (blockIdx.x >> 3) * 64;
  const unsigned short* W1e = W1t + (size_t)e * (256 * 64);
  const unsigned short* W2e = W2t + (size_t)e * (256 * 256);

  // --- state [64][64] f32 -> X1 bf16 (both sides in-kernel: swizzle freely)
  {
    const float4* sp = (const float4*)(stateF + (size_t)mtile * 64);
    #pragma unroll
    for (int i = 0; i < 4; ++i) {
      const int idx = i * 256 + tid;          // float4 index: row=idx>>4, k0=(idx&15)*4
      const float4 v = sp[idx];
      const int row = idx >> 4, k0 = (idx & 15) * 4;
      const int p = k0 >> 5, kin = k0 & 31;
      const int sl = swz_slot(row, kin >> 3);
      const ushort4 o = { f2bf(v.x), f2bf(v.y), f2bf(v.z), f2bf(v.w) };
      *(ushort4*)&X1[p * 2048 + row * 32 + sl * 8 + (kin & 7)] = o;
    }
  }
  // --- stage W1t (2 panels x 1024 slots)
  #pragma unroll
  for (int p = 0; p < 2; ++p)
    #pragma unroll
    for (int i = 0; i < 4; ++i) {
      const int s0 = wv * 64 + i * 256;
      const int s = s0 + lane;
      const int row = s >> 2;
      const int kap = swz_slot(row, s & 3);
      gload_lds16(W1e + (size_t)row * 64 + p * 32 + kap * 8, &X2[p * 8192 + s0 * 8]);
    }
  __syncthreads();

  // --- G1: 2 K-steps, pure MFMA (no mid barriers; buffers read-only)
  f32x4 acc1[2][8];
  #pragma unroll
  for (int i = 0; i < 2; ++i)
    #pragma unroll
    for (int j = 0; j < 8; ++j) acc1[i][j] = (f32x4){0.f, 0.f, 0.f, 0.f};
  #pragma unroll
  for (int p = 0; p < 2; ++p) {
    s16x8 av[2], bv[8];
    #pragma unroll
    for (int mi = 0; mi < 2; ++mi) {
      const int row = wr * 32 + mi * 16 + lr;
      av[mi] = *(const s16x8*)&X1[p * 2048 + row * 32 + swz_slot(row, lk) * 8];
    }
    #pragma unroll
    for (int nj = 0; nj < 8; ++nj) {
      const int col = wc * 128 + nj * 16 + lr;
      bv[nj] = *(const s16x8*)&X2[p * 8192 + col * 32 + swz_slot(col, lk) * 8];
    }
    __builtin_amdgcn_s_setprio(1);
    #pragma unroll
    for (int mi = 0; mi < 2; ++mi)
      #pragma unroll
      for (int nj = 0; nj < 8; ++nj)
        acc1[mi][nj] = __builtin_amdgcn_mfma_f32_16x16x32_bf16(av[mi], bv[nj], acc1[mi][nj], 0, 0, 0);
    __builtin_amdgcn_s_setprio(0);
  }
  __syncthreads();   // all waves done reading X2(W1t) before overwrite

  auto stageW2 = [&](int buf, int kk) {
    #pragma unroll
    for (int i = 0; i < 4; ++i) {
      const int s0 = wv * 64 + i * 256;
      const int s = s0 + lane;
      const int row = s >> 2;
      const int kap = swz_slot(row, s & 3);
      gload_lds16(W2e + (size_t)row * 256 + kk + kap * 8, &X3[buf][s0 * 8]);
    }
  };
  stageW2(0, 0);     // HBM latency hides under h1 LDS writes

  // --- h1 = tanh(acc1 + b1) -> X2 as 8 panels [64][32] (swizzled scalar writes)
  #pragma unroll
  for (int nj = 0; nj < 8; ++nj) {
    const int col = wc * 128 + nj * 16 + lr;
    const float bc = b1[e * 256 + col];
    #pragma unroll
    for (int mi = 0; mi < 2; ++mi)
      #pragma unroll
      for (int r = 0; r < 4; ++r) {
        const int row = wr * 32 + mi * 16 + lk * 4 + r;
        const float hv = fast_tanh(acc1[mi][nj][r] + bc);
        X2[(col >> 5) * 2048 + row * 32 + swz_slot(row, (col >> 3) & 3) * 8 + (col & 7)] = f2bf(hv);
      }
  }
  __syncthreads();   // h1 visible + X3[0] staged (vmcnt drained)

  // --- G2: 8 K-steps, A = h1 panels (static), B = W2t dbuf
  f32x4 acc2[2][8];
  #pragma unroll
  for (int i = 0; i < 2; ++i)
    #pragma unroll
    for (int j = 0; j < 8; ++j) acc2[i][j] = (f32x4){0.f, 0.f, 0.f, 0.f};
  #pragma unroll 2
  for (int t = 0; t < 8; ++t) {
    const int cur = t & 1;
    if (t < 7) stageW2(cur ^ 1, (t + 1) * 32);
    s16x8 av[2], bv[8];
    #pragma unroll
    for (int mi = 0; mi < 2; ++mi) {
      const int row = wr * 32 + mi * 16 + lr;
      av[mi] = *(const s16x8*)&X2[t * 2048 + row * 32 + swz_slot(row, lk) * 8];
    }
    #pragma unroll
    for (int nj = 0; nj < 8; ++nj) {
      const int col = wc * 128 + nj * 16 + lr;
      bv[nj] = *(const s16x8*)&X3[cur][col * 32 + swz_slot(col, lk) * 8];
    }
    __builtin_amdgcn_s_setprio(1);
    #pragma unroll
    for (int mi = 0; mi < 2; ++mi)
      #pragma unroll
      for (int nj = 0; nj < 8; ++nj)
        acc2[mi][nj] = __builtin_amdgcn_mfma_f32_16x16x32_bf16(av[mi], bv[nj], acc2[mi][nj], 0, 0, 0);
    __builtin_amdgcn_s_setprio(0);
    __syncthreads();
  }

  // --- epilogue: h2 = tanh(acc2 + b2) -> global bf16
  unsigned short* hout = h2B + (size_t)e * ((size_t)BSZ * HDIM) + (size_t)mtile * HDIM;
  #pragma unroll
  for (int nj = 0; nj < 8; ++nj) {
    const int col = wc * 128 + nj * 16 + lr;
    const float bc = b2[e * 256 + col];
    #pragma unroll
    for (int mi = 0; mi < 2; ++mi)
      #pragma unroll
      for (int r = 0; r < 4; ++r) {
        const int row = wr * 32 + mi * 16 + lk * 4 + r;
        hout[(size_t)row * HDIM + col] = f2bf(fast_tanh(acc2[mi][nj][r] + bc));
      }
  }
}

// ---------------- gemm_out: R2-verified loop; bias inlined in epilogue ------
// BM=128, BN=192, BK=32; 4 waves (2x2), wave owns 64x96 (acc[4][6]).
// Grid 768 = 3 blocks/CU exact. XCD-chunked remap (m-major per XCD chunk).
__global__ __launch_bounds__(256, 3) void gemm_out_kernel(
    const unsigned short* __restrict__ h2b,   // [E][B][256] bf16
    const unsigned short* __restrict__ Wcat,  // [1152][2048] bf16 (pad rows zeroed)
    const float* __restrict__ bfp,            // [E][64]
    const float* __restrict__ bgp,            // [E][1024]
    float* __restrict__ out) {
  __shared__ unsigned short As[2][4096];      // [128][32]
  __shared__ unsigned short Bs[2][6144];      // [192][32]
  const int tid = threadIdx.x;
  const int lane = tid & 63;
  const int wv = tid >> 6;
  const int wr = wv >> 1, wc = wv & 1;
  const int logical = (blockIdx.x & 7) * 96 + (blockIdx.x >> 3);
  const int mtile = (logical / 6) * 128;
  const int ntile = (logical % 6) * 192;
  const int lr = lane & 15, lk = lane >> 4;

  f32x4 acc[4][6];
  #pragma unroll
  for (int i = 0; i < 4; ++i)
    #pragma unroll
    for (int j = 0; j < 6; ++j) acc[i][j] = (f32x4){0.f, 0.f, 0.f, 0.f};

  auto stage = [&](int buf, int kk) {
    const int e = kk >> 8;
    const int kl = kk & 255;
    #pragma unroll
    for (int i = 0; i < 2; ++i) {       // A: 512 slots
      const int s0 = wv * 64 + i * 256;
      const int s = s0 + lane;
      const int row = s >> 2;
      const int kap = swz_slot(row, s & 3);
      gload_lds16(h2b + ((size_t)e * BSZ + mtile + row) * HDIM + (kl + kap * 8),
                  &As[buf][s0 * 8]);
    }
    #pragma unroll
    for (int i = 0; i < 3; ++i) {       // B: 768 slots
      const int s0 = wv * 64 + i * 256;
      const int s = s0 + lane;
      const int row = s >> 2;
      const int kap = swz_slot(row, s & 3);
      gload_lds16(Wcat + (size_t)(ntile + row) * KCAT + (kk + kap * 8),
                  &Bs[buf][s0 * 8]);
    }
  };

  stage(0, 0);
  __syncthreads();
  constexpr int NSTEP = KCAT / 32;      // 64
  #pragma unroll 2
  for (int t = 0; t < NSTEP; ++t) {
    const int cur = t & 1;
    if (t + 1 < NSTEP) stage(cur ^ 1, (t + 1) * 32);
    s16x8 av[4], bv[6];
    #pragma unroll
    for (int mi = 0; mi < 4; ++mi) {
      const int r = wr * 64 + mi * 16 + lr;
      av[mi] = *(const s16x8*)&As[cur][r * 32 + swz_slot(r, lk) * 8];
    }
    #pragma unroll
    for (int nj = 0; nj < 6; ++nj) {
      const int r = wc * 96 + nj * 16 + lr;
      bv[nj] = *(const s16x8*)&Bs[cur][r * 32 + swz_slot(r, lk) * 8];
    }
    __builtin_amdgcn_s_setprio(1);
    #pragma unroll
    for (int mi = 0; mi < 4; ++mi)
      #pragma unroll
      for (int nj = 0; nj < 6; ++nj)
        acc[mi][nj] = __builtin_amdgcn_mfma_f32_16x16x32_bf16(av[mi], bv[nj], acc[mi][nj], 0, 0, 0);
    __builtin_amdgcn_s_setprio(0);
    __syncthreads();
  }

  #pragma unroll
  for (int nj = 0; nj < 6; ++nj) {
    const int col = ntile + wc * 96 + nj * 16 + lr;
    if (col < NOUT) {
      float bc = 0.f;
      #pragma unroll
      for (int ee = 0; ee < EDIM; ++ee)
        bc += (col < SDIM) ? bfp[ee * SDIM + col] : bgp[ee * 1024 + (col - SDIM)];
      bc *= 0.125f;
      #pragma unroll
      for (int mi = 0; mi < 4; ++mi)
        #pragma unroll
        for (int r = 0; r < 4; ++r) {
          const int row = mtile + wr * 64 + mi * 16 + lk * 4 + r;
          const float v = acc[mi][nj][r] * 0.125f + bc;
          if (col < SDIM) out[(size_t)row * SDIM + col] = v;                         // f_mean
          else out[(size_t)BSZ * SDIM + (size_t)row * 1024 + (col - SDIM)] = v;      // g_mean
        }
    }
  }
}

// ---------------- launch ----------------

extern "C" void kernel_launch(void* const* d_in, const int* in_sizes, int n_in,
                              void* d_out, int out_size, void* d_ws, size_t ws_size,
                              hipStream_t stream) {
  (void)in_sizes; (void)n_in; (void)out_size;
  const float* state = (const float*)d_in[0];
  const float* W1 = (const float*)d_in[1];
  const float* b1 = (const float*)d_in[2];
  const float* W2 = (const float*)d_in[3];
  const float* b2 = (const float*)d_in[4];
  const float* Wf = (const float*)d_in[5];
  const float* bf = (const float*)d_in[6];
  const float* Wg = (const float*)d_in[7];
  const float* bg = (const float*)d_in[8];
  float* out = (float*)d_out;

  // ws layout (bytes)
  const size_t SZ_H2   = (size_t)EDIM * BSZ * HDIM * 2;          // 64 MB
  const size_t SZ_W1T  = (size_t)EDIM * HDIM * SDIM * 2;         // 256 KB
  const size_t SZ_W2T  = (size_t)EDIM * HDIM * HDIM * 2;         // 1 MB
  const size_t SZ_WCAT = (size_t)NPAD * KCAT * 2;                // 4.5 MB
  const size_t OFF_H2 = 0;
  const size_t OFF_W1T = OFF_H2 + SZ_H2;
  const size_t OFF_W2T = OFF_W1T + SZ_W1T;
  const size_t OFF_WCAT = OFF_W2T + SZ_W2T;
  const size_t TOTAL = OFF_WCAT + SZ_WCAT;                       // ~69.8 MB
  if (ws_size < TOTAL) return;

  char* ws = (char*)d_ws;
  unsigned short* h2B  = (unsigned short*)(ws + OFF_H2);
  unsigned short* W1t  = (unsigned short*)(ws + OFF_W1T);
  unsigned short* W2t  = (unsigned short*)(ws + OFF_W2T);
  unsigned short* Wcat = (unsigned short*)(ws + OFF_WCAT);

  prep_kernel<<<2880, 256, 0, stream>>>(W1, W2, Wf, Wg, W1t, W2t, Wcat);
  gemm12_kernel<<<2048, 256, 0, stream>>>(state, W1t, b1, W2t, b2, h2B);
  gemm_out_kernel<<<768, 256, 0, stream>>>(h2B, Wcat, bf, bg, out);
}